// Round 11
// baseline (373.090 us; speedup 1.0000x reference)
//
#include <hip/hip_runtime.h>
#include <hip/hip_bf16.h>

// Problem constants
#define BATCH   1024
#define FDIM    2048
#define LDIM    80
#define EDIM    512
#define ODIM    2048
#define NEXP    8
#define INDIM   2560   // FDIM + EDIM

// GEMM geometry (8-phase 256^2 template)
#define BM      256
#define BN      256
#define BK      64
#define NKT     (INDIM / BK)   // 40 K-tiles

typedef __bf16 bf16x8 __attribute__((ext_vector_type(8)));
typedef float  f32x4  __attribute__((ext_vector_type(4)));

__device__ __forceinline__ unsigned int pack2(float lo, float hi) {
    __hip_bfloat162 h = __float22bfloat162_rn(make_float2(lo, hi));
    unsigned int u;
    __builtin_memcpy(&u, &h, 4);
    return u;
}
__device__ __forceinline__ float bf2f(unsigned short h) {
    return __uint_as_float((unsigned int)h << 16);
}
__device__ __forceinline__ void gload_lds16(const void* g, void* l) {
    __builtin_amdgcn_global_load_lds(
        (__attribute__((address_space(1))) void*)g,
        (__attribute__((address_space(3))) void*)l,
        16, 0, 0);
}

#define BAR()       __builtin_amdgcn_s_barrier()
#define SCHED_PIN() __builtin_amdgcn_sched_barrier(0)

// convert tile geometry
#define CW_TK 128   // k rows per tile
#define CW_TO 64    // o cols per tile
#define CW_BLOCKS  ((ODIM / CW_TO) * (INDIM / CW_TK) * NEXP)   // 32*20*8 = 5120
#define PREP_BLOCKS (BATCH / 4)                                 // 256
#define GATE_BLOCKS (BATCH)                                     // 1024
#define FRONT_BLOCKS (CW_BLOCKS + PREP_BLOCKS + GATE_BLOCKS)    // 6400

// ---------------------------------------------------------------------------
// Kernel F (fused front): prep + gate + convert_w in ONE launch, partitioned
// by blockIdx. ROLE ORDER CHANGED this round: prep (0..255) and gate
// (256..1279) dispatch FIRST, convert (1280..6399) after. R10 showed the
// latency-bound gate role (80-iter serial label_embed loop, ~4us/block,
// 4 rounds deep) ran as a ~15-20us SERIAL TAIL after convert's HBM phase;
// dispatching it first hides those loads under convert's BW shadow
// (convert: VALUBusy 8%, MfmaUtil 0 — idle latency-hiding capacity).
// ---------------------------------------------------------------------------
__global__ __launch_bounds__(256) void front_kernel(
    const float* __restrict__ W, unsigned short* __restrict__ Wb,
    const float* __restrict__ features, const float* __restrict__ labels,
    const float* __restrict__ label_embed, unsigned short* __restrict__ cb,
    const float* __restrict__ gw, const float* __restrict__ gb,
    float* __restrict__ gating)
{
    __shared__ float smem[CW_TK * CW_TO];      // 32 KiB flat, overlaid per role
    const int bid = blockIdx.x;
    const int t   = threadIdx.x;

    if (bid >= PREP_BLOCKS + GATE_BLOCKS) {
        // ---------------- convert role: W fp32 [e][k][o] -> Wb bf16 [e][o][k]
        const int cwb = bid - (PREP_BLOCKS + GATE_BLOCKS);
        const int o0 = (cwb & 31) * CW_TO;
        const int k0 = ((cwb >> 5) % (INDIM / CW_TK)) * CW_TK;
        const int e  = cwb / ((ODIM / CW_TO) * (INDIM / CW_TK));

        // stage: thread t covers (row = p*16 + (t>>4), chunk = t&15);
        // LDS linear = row*256B + chunk*16B; global chunk pre-swizzled (T2).
        const int rr = t >> 4;
        const int cc = t & 15;
        const float* srcbase = W + (size_t)e * ((size_t)INDIM * ODIM)
                                 + (size_t)k0 * ODIM + o0;
        float* ldsbase = smem + (t >> 6) * 256;   // wave-uniform
        #pragma unroll
        for (int p = 0; p < 8; ++p) {
            const int row = p * 16 + rr;
            const int cs  = cc ^ ((row >> 3) & 15);
            gload_lds16(srcbase + (size_t)row * ODIM + cs * 4,
                        ldsbase + p * 1024);
        }
        __syncthreads();   // vmcnt(0) drain before barrier — wanted here

        // write: o-row = t>>2, 64B chunk c = t&3; swizzled transpose reads.
        const int o = t >> 2;
        const int c = t & 3;
        unsigned short* dst = Wb + (size_t)e * ((size_t)ODIM * INDIM)
                                 + (size_t)(o0 + o) * INDIM + k0 + c * 32;
        #pragma unroll
        for (int u = 0; u < 4; ++u) {
            const int kb = c * 32 + u * 8;               // octet-aligned
            const int x  = (kb >> 3) & 15;               // constant over octet
            const float* tp = smem + (size_t)kb * 64 + (((o >> 2) ^ x) << 2) + (o & 3);
            unsigned int w0 = pack2(tp[0 * 64], tp[1 * 64]);
            unsigned int w1 = pack2(tp[2 * 64], tp[3 * 64]);
            unsigned int w2 = pack2(tp[4 * 64], tp[5 * 64]);
            unsigned int w3 = pack2(tp[6 * 64], tp[7 * 64]);
            ((uint4*)dst)[u] = make_uint4(w0, w1, w2, w3);
        }
    } else if (bid < PREP_BLOCKS) {
        // ---------------- prep role: cb = [features | labels @ label_embed] bf16
        const int b0 = bid * 4;
        float (*lab)[LDIM] = (float(*)[LDIM])smem;
        for (int idx = t; idx < 4 * LDIM; idx += 256) {
            lab[idx / LDIM][idx % LDIM] = labels[(size_t)(b0 + idx / LDIM) * LDIM + (idx % LDIM)];
        }
        __syncthreads();
        {
            const int r = t >> 6, c64 = t & 63;
            const float4* F4 = (const float4*)features;
            #pragma unroll
            for (int ch = 0; ch < 8; ++ch) {
                float4 v = F4[(size_t)(b0 + r) * (FDIM / 4) + c64 + 64 * ch];
                uint2 pk;
                pk.x = pack2(v.x, v.y);
                pk.y = pack2(v.z, v.w);
                *(uint2*)(cb + (size_t)(b0 + r) * INDIM + (size_t)(c64 + 64 * ch) * 4) = pk;
            }
        }
        {
            const int j = 2 * t;
            float acc[4][2] = {{0,0},{0,0},{0,0},{0,0}};
            const float2* le2 = (const float2*)label_embed;
            for (int l = 0; l < LDIM; ++l) {
                float2 le = le2[(size_t)l * (EDIM / 2) + t];
                #pragma unroll
                for (int r = 0; r < 4; ++r) {
                    float lv = lab[r][l];
                    acc[r][0] += lv * le.x;
                    acc[r][1] += lv * le.y;
                }
            }
            #pragma unroll
            for (int r = 0; r < 4; ++r) {
                *(unsigned int*)(cb + (size_t)(b0 + r) * INDIM + FDIM + j) = pack2(acc[r][0], acc[r][1]);
            }
        }
    } else {
        // ---------------- gate role: gating = sigmoid([F | labels@E] @ gw + gb)
        const int b = bid - PREP_BLOCKS;
        float* labs = smem;                               // [80]
        float (*red)[NEXP] = (float(*)[NEXP])(smem + 128);
        if (t < LDIM) labs[t] = labels[(size_t)b * LDIM + t];
        __syncthreads();

        float p[NEXP] = {0,0,0,0,0,0,0,0};
        for (int i = t; i < FDIM; i += 256) {
            float c = features[(size_t)b * FDIM + i];
            const float4* g4 = (const float4*)(gw + (size_t)i * NEXP);
            float4 u = g4[0], v = g4[1];
            p[0] += c * u.x; p[1] += c * u.y; p[2] += c * u.z; p[3] += c * u.w;
            p[4] += c * v.x; p[5] += c * v.y; p[6] += c * v.z; p[7] += c * v.w;
        }
        float le0 = 0.f, le1 = 0.f;
        #pragma unroll 8
        for (int l = 0; l < LDIM; ++l) {
            float lv = labs[l];
            le0 += lv * label_embed[(size_t)l * EDIM + t];
            le1 += lv * label_embed[(size_t)l * EDIM + t + 256];
        }
        {
            const float4* g4 = (const float4*)(gw + (size_t)(FDIM + t) * NEXP);
            float4 u = g4[0], v = g4[1];
            p[0] += le0 * u.x; p[1] += le0 * u.y; p[2] += le0 * u.z; p[3] += le0 * u.w;
            p[4] += le0 * v.x; p[5] += le0 * v.y; p[6] += le0 * v.z; p[7] += le0 * v.w;
            const float4* g5 = (const float4*)(gw + (size_t)(FDIM + 256 + t) * NEXP);
            float4 u2 = g5[0], v2 = g5[1];
            p[0] += le1 * u2.x; p[1] += le1 * u2.y; p[2] += le1 * u2.z; p[3] += le1 * u2.w;
            p[4] += le1 * v2.x; p[5] += le1 * v2.y; p[6] += le1 * v2.z; p[7] += le1 * v2.w;
        }
        const int lane = t & 63, wave = t >> 6;
        #pragma unroll
        for (int e = 0; e < NEXP; ++e) {
            float v = p[e];
            v += __shfl_down(v, 32); v += __shfl_down(v, 16); v += __shfl_down(v, 8);
            v += __shfl_down(v, 4);  v += __shfl_down(v, 2);  v += __shfl_down(v, 1);
            if (lane == 0) red[wave][e] = v;
        }
        __syncthreads();
        if (t < NEXP) {
            float s = red[0][t] + red[1][t] + red[2][t] + red[3][t] + gb[t];
            gating[(size_t)b * NEXP + t] = 1.0f / (1.0f + __expf(-s));
        }
    }
}

// ---------------------------------------------------------------------------
// Kernel 1/2 (retained for the small-ws fallback path only)
// ---------------------------------------------------------------------------
__global__ __launch_bounds__(256) void prep_kernel(
    const float* __restrict__ features, const float* __restrict__ labels,
    const float* __restrict__ label_embed, unsigned short* __restrict__ cb)
{
    const int b0 = blockIdx.x * 4;
    const int t  = threadIdx.x;
    __shared__ float lab[4][LDIM];
    for (int idx = t; idx < 4 * LDIM; idx += 256) {
        lab[idx / LDIM][idx % LDIM] = labels[(size_t)(b0 + idx / LDIM) * LDIM + (idx % LDIM)];
    }
    __syncthreads();

    {
        const int r = t >> 6, c64 = t & 63;
        const float4* F4 = (const float4*)features;
        #pragma unroll
        for (int ch = 0; ch < 8; ++ch) {
            float4 v = F4[(size_t)(b0 + r) * (FDIM / 4) + c64 + 64 * ch];
            uint2 pk;
            pk.x = pack2(v.x, v.y);
            pk.y = pack2(v.z, v.w);
            *(uint2*)(cb + (size_t)(b0 + r) * INDIM + (size_t)(c64 + 64 * ch) * 4) = pk;
        }
    }
    {
        const int j = 2 * t;
        float acc[4][2] = {{0,0},{0,0},{0,0},{0,0}};
        const float2* le2 = (const float2*)label_embed;
        for (int l = 0; l < LDIM; ++l) {
            float2 le = le2[(size_t)l * (EDIM / 2) + t];
            #pragma unroll
            for (int r = 0; r < 4; ++r) {
                float lv = lab[r][l];
                acc[r][0] += lv * le.x;
                acc[r][1] += lv * le.y;
            }
        }
        #pragma unroll
        for (int r = 0; r < 4; ++r) {
            *(unsigned int*)(cb + (size_t)(b0 + r) * INDIM + FDIM + j) = pack2(acc[r][0], acc[r][1]);
        }
    }
}

__global__ __launch_bounds__(256) void gate_kernel(
    const unsigned short* __restrict__ cb, const float* __restrict__ gw,
    const float* __restrict__ gb, float* __restrict__ gating)
{
    const int b = blockIdx.x, t = threadIdx.x;
    float p[NEXP] = {0,0,0,0,0,0,0,0};
    for (int i = t; i < INDIM; i += 256) {
        float c = bf2f(cb[(size_t)b * INDIM + i]);
        const float4* g4 = (const float4*)(gw + (size_t)i * NEXP);
        float4 u = g4[0], v = g4[1];
        p[0] += c * u.x; p[1] += c * u.y; p[2] += c * u.z; p[3] += c * u.w;
        p[4] += c * v.x; p[5] += c * v.y; p[6] += c * v.z; p[7] += c * v.w;
    }
    __shared__ float red[4][NEXP];
    const int lane = t & 63, wave = t >> 6;
    #pragma unroll
    for (int e = 0; e < NEXP; ++e) {
        float v = p[e];
        v += __shfl_down(v, 32); v += __shfl_down(v, 16); v += __shfl_down(v, 8);
        v += __shfl_down(v, 4);  v += __shfl_down(v, 2);  v += __shfl_down(v, 1);
        if (lane == 0) red[wave][e] = v;
    }
    __syncthreads();
    if (t < NEXP) {
        float s = red[0][t] + red[1][t] + red[2][t] + red[3][t] + gb[t];
        gating[(size_t)b * NEXP + t] = 1.0f / (1.0f + __expf(-s));
    }
}

// ---------------------------------------------------------------------------
// Kernel 3 (fast path): 256x256 8-phase pipelined MFMA GEMM (unchanged R6/R7
// K-loop; non-atomic epilogue writes gated+biased partials — R7-confirmed win).
// ---------------------------------------------------------------------------
template<bool ATOMIC>
__global__ __launch_bounds__(512, 2) void moe_gemm8(
    const unsigned short* __restrict__ cb, const unsigned short* __restrict__ Wb,
    const float* __restrict__ gating, const float* __restrict__ eb,
    float* __restrict__ dst)
{
    __shared__ unsigned short As0[256 * 64];   // 32 KiB each, 128 KiB total
    __shared__ unsigned short Bs0[256 * 64];
    __shared__ unsigned short As1[256 * 64];
    __shared__ unsigned short Bs1[256 * 64];

    const int t = threadIdx.x;
    const int lane = t & 63, wave = t >> 6;
    const int n0 = blockIdx.x * BN;
    const int m0 = blockIdx.y * BM;
    const int e  = blockIdx.z;

    const int wmi = wave >> 2;            // 0..1
    const int wni = wave & 3;             // 0..3
    const int wmBase = wmi * 128;
    const int wnBase = wni * 64;
    const int fm = lane & 15, fq = lane >> 4;
    const int fsw = fm & 7;               // row&7 for all fragment rows

    const int srow = t >> 3;                        // 0..63
    const int scn  = (t & 7) ^ (srow & 7);
    const size_t gOff = (size_t)srow * INDIM + (size_t)scn * 8;
    const unsigned short* aS = cb + (size_t)m0 * INDIM + gOff;
    const unsigned short* bS = Wb + (size_t)e * ((size_t)ODIM * INDIM)
                                  + (size_t)n0 * INDIM + gOff;

    #define STAGE4_A(DST, kt) { _Pragma("unroll") for (int q = 0; q < 4; ++q) \
        gload_lds16(aS + (size_t)q * (64 * INDIM) + (size_t)(kt) * 64, (DST) + q * 4096 + wave * 512); }
    #define STAGE4_B(DST, kt) { _Pragma("unroll") for (int q = 0; q < 4; ++q) \
        gload_lds16(bS + (size_t)q * (64 * INDIM) + (size_t)(kt) * 64, (DST) + q * 4096 + wave * 512); }

    #define PH_READ_A(RA, base) { _Pragma("unroll") for (int mi = 0; mi < 4; ++mi) \
        _Pragma("unroll") for (int ks = 0; ks < 2; ++ks) \
            af[mi][ks] = *(const bf16x8*)((RA) + (wmBase + (base) + mi * 16 + fm) * 64 \
                                               + (((ks * 4 + fq) ^ fsw) * 8)); }
    #define PH_READ_B(BF, RB, base) { _Pragma("unroll") for (int ni = 0; ni < 2; ++ni) \
        _Pragma("unroll") for (int ks = 0; ks < 2; ++ks) \
            BF[ni][ks] = *(const bf16x8*)((RB) + (wnBase + (base) + ni * 16 + fm) * 64 \
                                               + (((ks * 4 + fq) ^ fsw) * 8)); }
    #define MFMA16(AI, AJ, BF) { __builtin_amdgcn_s_setprio(1); \
        _Pragma("unroll") for (int mi = 0; mi < 4; ++mi) \
        _Pragma("unroll") for (int ni = 0; ni < 2; ++ni) \
        _Pragma("unroll") for (int ks = 0; ks < 2; ++ks) \
            acc[(AI) + mi][(AJ) + ni] = __builtin_amdgcn_mfma_f32_16x16x32_bf16( \
                af[mi][ks], BF[ni][ks], acc[(AI) + mi][(AJ) + ni], 0, 0, 0); \
        __builtin_amdgcn_s_setprio(0); }

    f32x4 acc[8][4];
    #pragma unroll
    for (int i = 0; i < 8; ++i)
        #pragma unroll
        for (int j = 0; j < 4; ++j) acc[i][j] = (f32x4){0.f, 0.f, 0.f, 0.f};

    bf16x8 af[4][2], bA[2][2], bB[2][2];

    // Prologue: T0 fully -> As0/Bs0 (8), T1's B -> Bs1 (4).
    STAGE4_A(As0, 0); STAGE4_B(Bs0, 0); STAGE4_B(Bs1, 1);
    asm volatile("s_waitcnt vmcnt(4)");   // T0 resident; T1-B stays in flight
    BAR(); SCHED_PIN();

    #define TILE(kt, RA, RB, OA) { \
        /* phase 1: C(mh0,nh0) */ \
        PH_READ_A(RA, 0); \
        PH_READ_B(bA, RB, 0); \
        if ((kt) + 1 < NKT) STAGE4_A(OA, (kt) + 1); \
        BAR(); \
        MFMA16(0, 0, bA); \
        SCHED_PIN(); BAR(); SCHED_PIN(); \
        /* phase 2: C(mh0,nh1) */ \
        PH_READ_B(bB, RB, 32); \
        BAR(); \
        MFMA16(0, 2, bB); \
        SCHED_PIN(); BAR(); SCHED_PIN(); \
        /* phase 3: C(mh1,nh1) */ \
        PH_READ_A(RA, 64); \
        BAR(); \
        MFMA16(4, 2, bB); \
        SCHED_PIN(); BAR(); SCHED_PIN(); \
        /* phase 4: C(mh1,nh0); stage next-next B into cur-B (reads done ph2) */ \
        if ((kt) + 2 < NKT) STAGE4_B(RB, (kt) + 2); \
        BAR(); \
        MFMA16(4, 0, bA); \
        SCHED_PIN(); \
        if ((kt) + 2 < NKT) { asm volatile("s_waitcnt vmcnt(4)"); } \
        else                { asm volatile("s_waitcnt vmcnt(0)"); } \
        BAR(); SCHED_PIN(); \
    }

    for (int kt = 0; kt < NKT; kt += 2) {
        TILE(kt,     As0, Bs0, As1);
        TILE(kt + 1, As1, Bs1, As0);
    }
    #undef TILE
    #undef STAGE4_A
    #undef STAGE4_B
    #undef PH_READ_A
    #undef PH_READ_B
    #undef MFMA16

    // Epilogue: gate-scale + gated bias.
    #pragma unroll
    for (int mi = 0; mi < 8; ++mi) {
        const int grow = m0 + wmBase + mi * 16 + fq * 4;
        const float g0 = gating[(size_t)(grow + 0) * NEXP + e];
        const float g1 = gating[(size_t)(grow + 1) * NEXP + e];
        const float g2 = gating[(size_t)(grow + 2) * NEXP + e];
        const float g3 = gating[(size_t)(grow + 3) * NEXP + e];
        #pragma unroll
        for (int ni = 0; ni < 4; ++ni) {
            const int gcol = n0 + wnBase + ni * 16 + fm;
            const float bias = eb[(size_t)e * ODIM + gcol];
            f32x4 a = acc[mi][ni];
            if (ATOMIC) {
                unsafeAtomicAdd(dst + (size_t)(grow + 0) * ODIM + gcol, g0 * (a.x + bias));
                unsafeAtomicAdd(dst + (size_t)(grow + 1) * ODIM + gcol, g1 * (a.y + bias));
                unsafeAtomicAdd(dst + (size_t)(grow + 2) * ODIM + gcol, g2 * (a.z + bias));
                unsafeAtomicAdd(dst + (size_t)(grow + 3) * ODIM + gcol, g3 * (a.w + bias));
            } else {
                float* pd = dst + ((size_t)e * BATCH + grow) * ODIM + gcol;
                pd[0 * ODIM] = g0 * (a.x + bias);
                pd[1 * ODIM] = g1 * (a.y + bias);
                pd[2 * ODIM] = g2 * (a.z + bias);
                pd[3 * ODIM] = g3 * (a.w + bias);
            }
        }
    }
}

// ---------------------------------------------------------------------------
// Kernel 4: out[m][n] = sum_e parts[e][m][n]. Streaming, float4, ~72 MB.
// ---------------------------------------------------------------------------
__global__ __launch_bounds__(256) void combine_kernel(
    const float* __restrict__ parts, float* __restrict__ out)
{
    const int idx = blockIdx.x * 256 + threadIdx.x;    // one float4 per thread
    const float4* p = (const float4*)parts;
    float4 s = p[idx];
    #pragma unroll
    for (int e = 1; e < NEXP; ++e) {
        float4 v = p[(size_t)e * (BATCH * ODIM / 4) + idx];
        s.x += v.x; s.y += v.y; s.z += v.z; s.w += v.w;
    }
    ((float4*)out)[idx] = s;
}

// ---------------------------------------------------------------------------
// Kernel 3 (fallback, small-ws): in-loop fp32->bf16 W staging (unchanged)
// ---------------------------------------------------------------------------
__global__ __launch_bounds__(256) void moe_gemm_slow(
    const unsigned short* __restrict__ cb, const float* __restrict__ W,
    const float* __restrict__ gating, const float* __restrict__ eb,
    float* __restrict__ out)
{
    __shared__ unsigned short As[128 * 32];
    __shared__ unsigned short Bs[128 * 32];

    const int t = threadIdx.x;
    const int lane = t & 63, wave = t >> 6;
    const int n0 = blockIdx.x * 128;
    const int m0 = blockIdx.y * 128;
    const int e  = blockIdx.z;

    f32x4 acc[4][4];
    #pragma unroll
    for (int i = 0; i < 4; ++i)
        #pragma unroll
        for (int j = 0; j < 4; ++j) acc[i][j] = (f32x4){0.f, 0.f, 0.f, 0.f};

    const int arow = t >> 2, acg = t & 3;
    const unsigned short* ag0 = cb + (size_t)(m0 + arow) * INDIM + acg * 8;
    unsigned short* al0 = As + wave * 512;
    unsigned short* al1 = As + 2048 + wave * 512;

    const int bg = t & 15;
    const int bu = t >> 4;
    const float* wg = W + (size_t)e * ((size_t)INDIM * ODIM) + (size_t)(2 * bg) * ODIM + n0 + bu * 8;
    unsigned int* bl = (unsigned int*)Bs + bg + bu * 128;

    const int fm = lane & 15, fq = lane >> 4;
    const int wn = (wave & 1) * 64;
    const int wm = (wave >> 1) * 64;

    for (int k0 = 0; k0 < INDIM; k0 += 32) {
        __syncthreads();
        gload_lds16(ag0 + k0, al0);
        gload_lds16(ag0 + (size_t)64 * INDIM + k0, al1);
        const float* wp = wg + (size_t)k0 * ODIM;
        float4 r0a = *(const float4*)(wp);
        float4 r0b = *(const float4*)(wp + 4);
        float4 r1a = *(const float4*)(wp + ODIM);
        float4 r1b = *(const float4*)(wp + ODIM + 4);
        bl[0 * 16] = pack2(r0a.x, r1a.x);
        bl[1 * 16] = pack2(r0a.y, r1a.y);
        bl[2 * 16] = pack2(r0a.z, r1a.z);
        bl[3 * 16] = pack2(r0a.w, r1a.w);
        bl[4 * 16] = pack2(r0b.x, r1b.x);
        bl[5 * 16] = pack2(r0b.y, r1b.y);
        bl[6 * 16] = pack2(r0b.z, r1b.z);
        bl[7 * 16] = pack2(r0b.w, r1b.w);
        __syncthreads();

        bf16x8 af[4], bfr[4];
        #pragma unroll
        for (int mi = 0; mi < 4; ++mi)
            af[mi] = *(const bf16x8*)(As + (wm + mi * 16 + fm) * 32 + fq * 8);
        #pragma unroll
        for (int ni = 0; ni < 4; ++ni)
            bfr[ni] = *(const bf16x8*)(Bs + (wn + ni * 16 + fm) * 32 + fq * 8);
        #pragma unroll
        for (int mi = 0; mi < 4; ++mi)
            #pragma unroll
            for (int ni = 0; ni < 4; ++ni)
                acc[mi][ni] = __builtin_amdgcn_mfma_f32_16x16x32_bf16(af[mi], bfr[ni], acc[mi][ni], 0, 0, 0);
    }

    #pragma unroll
    for (int mi = 0; mi < 4; ++mi) {
        const int grow = m0 + wm + mi * 16 + fq * 4;
        const float g0 = gating[(size_t)(grow + 0) * NEXP + e];
        const float g1 = gating[(size_t)(grow + 1) * NEXP + e];
        const float g2 = gating[(size_t)(grow + 2) * NEXP + e];
        const float g3 = gating[(size_t)(grow + 3) * NEXP + e];
        #pragma unroll
        for (int ni = 0; ni < 4; ++ni) {
            const int gcol = n0 + wn + ni * 16 + fm;
            const float bias = eb[(size_t)e * ODIM + gcol];
            f32x4 a = acc[mi][ni];
            unsafeAtomicAdd(out + (size_t)(grow + 0) * ODIM + gcol, g0 * (a.x + bias));
            unsafeAtomicAdd(out + (size_t)(grow + 1) * ODIM + gcol, g1 * (a.y + bias));
            unsafeAtomicAdd(out + (size_t)(grow + 2) * ODIM + gcol, g2 * (a.z + bias));
            unsafeAtomicAdd(out + (size_t)(grow + 3) * ODIM + gcol, g3 * (a.w + bias));
        }
    }
}

// ---------------------------------------------------------------------------
extern "C" void kernel_launch(void* const* d_in, const int* in_sizes, int n_in,
                              void* d_out, int out_size, void* d_ws, size_t ws_size,
                              hipStream_t stream) {
    const float* features    = (const float*)d_in[0];
    const float* labels      = (const float*)d_in[1];
    const float* label_embed = (const float*)d_in[2];
    const float* gate_w      = (const float*)d_in[3];
    const float* gate_b      = (const float*)d_in[4];
    const float* expert_w    = (const float*)d_in[5];
    const float* expert_b    = (const float*)d_in[6];
    float* out = (float*)d_out;

    // ws layout: Wb bf16 [8][2048][2560] | cb bf16 [1024][2560] | gating f32 |
    //            parts f32 [8][1024][2048]  (parts only on the fast2 path)
    const size_t wb_bytes = (size_t)NEXP * ODIM * INDIM * 2;        // 83,886,080
    const size_t cb_bytes = (size_t)BATCH * INDIM * 2;              //  5,242,880
    const size_t gt_bytes = (size_t)BATCH * NEXP * 4;               //     32,768
    const size_t pt_bytes = (size_t)NEXP * BATCH * ODIM * 4;        // 67,108,864
    const bool fast  = ws_size >= wb_bytes + cb_bytes + gt_bytes;
    const bool fast2 = ws_size >= wb_bytes + cb_bytes + gt_bytes + pt_bytes;

    if (fast) {
        unsigned short* Wb = (unsigned short*)d_ws;
        unsigned short* cb = (unsigned short*)((char*)d_ws + wb_bytes);
        float* gating = (float*)((char*)d_ws + wb_bytes + cb_bytes);
        float* parts  = (float*)((char*)d_ws + wb_bytes + cb_bytes + gt_bytes);
        front_kernel<<<FRONT_BLOCKS, 256, 0, stream>>>(
            expert_w, Wb, features, labels, label_embed, cb, gate_w, gate_b, gating);
        if (fast2) {
            moe_gemm8<false><<<dim3(ODIM / BN, BATCH / BM, NEXP), 512, 0, stream>>>(cb, Wb, gating, expert_b, parts);
            combine_kernel<<<(BATCH * ODIM / 4) / 256, 256, 0, stream>>>(parts, out);
        } else {
            hipMemsetAsync(d_out, 0, (size_t)BATCH * ODIM * sizeof(float), stream);
            moe_gemm8<true><<<dim3(ODIM / BN, BATCH / BM, NEXP), 512, 0, stream>>>(cb, Wb, gating, expert_b, out);
        }
    } else {
        unsigned short* cb = (unsigned short*)d_ws;
        float* gating = (float*)((char*)d_ws + cb_bytes);
        hipMemsetAsync(d_out, 0, (size_t)BATCH * ODIM * sizeof(float), stream);
        prep_kernel<<<BATCH / 4, 256, 0, stream>>>(features, labels, label_embed, cb);
        gate_kernel<<<BATCH, 256, 0, stream>>>(cb, gate_w, gate_b, gating);
        moe_gemm_slow<<<dim3(ODIM / 128, BATCH / 128, NEXP), 256, 0, stream>>>(cb, expert_w, gating, expert_b, out);
    }
}

// Round 15
// 372.321 us; speedup vs baseline: 1.0021x; 1.0021x over previous
//
#include <hip/hip_runtime.h>
#include <hip/hip_bf16.h>

// Problem constants
#define BATCH   1024
#define FDIM    2048
#define LDIM    80
#define EDIM    512
#define ODIM    2048
#define NEXP    8
#define INDIM   2560   // FDIM + EDIM

// GEMM geometry (8-phase 256^2 template)
#define BM      256
#define BN      256
#define BK      64
#define NKT     (INDIM / BK)   // 40 K-tiles

typedef __bf16 bf16x8 __attribute__((ext_vector_type(8)));
typedef float  f32x4  __attribute__((ext_vector_type(4)));

__device__ __forceinline__ unsigned int pack2(float lo, float hi) {
    __hip_bfloat162 h = __float22bfloat162_rn(make_float2(lo, hi));
    unsigned int u;
    __builtin_memcpy(&u, &h, 4);
    return u;
}
__device__ __forceinline__ float bf2f(unsigned short h) {
    return __uint_as_float((unsigned int)h << 16);
}
__device__ __forceinline__ void gload_lds16(const void* g, void* l) {
    __builtin_amdgcn_global_load_lds(
        (__attribute__((address_space(1))) void*)g,
        (__attribute__((address_space(3))) void*)l,
        16, 0, 0);
}

#define BAR()       __builtin_amdgcn_s_barrier()
#define SCHED_PIN() __builtin_amdgcn_sched_barrier(0)

// convert tile geometry v4: 64 k-rows x 128 o-cols (was 128x64).
// Read granule per wave-instr: 2 rows x 512B contiguous (was 4 x 256B) —
// 2x DRAM page locality. Write granule: 128B exact cache lines. Transpose
// reads are conflict-free WITHOUT swizzle (bank = o mod 32; 64 lanes cover
// 32 o twice = 2-way = free, m136).
#define CW_TK 64    // k rows per tile
#define CW_TO 128   // o cols per tile
#define CW_BLOCKS  ((ODIM / CW_TO) * (INDIM / CW_TK) * NEXP)   // 16*40*8 = 5120
#define PREP_BLOCKS (BATCH / 4)                                 // 256
#define GATE_BLOCKS (BATCH)                                     // 1024
#define FRONT_BLOCKS (CW_BLOCKS + PREP_BLOCKS + GATE_BLOCKS)    // 6400

// ---------------------------------------------------------------------------
// Kernel F (fused front): prep + gate + convert_w in ONE launch, partitioned
// by blockIdx (prep 0..255, gate 256..1279, convert 1280..6399).
// R10/R11 established: conflicts and role order are NOT the front bottleneck
// (both nulls at ~105us). This round targets the convert role's DRAM pattern.
// ---------------------------------------------------------------------------
__global__ __launch_bounds__(256) void front_kernel(
    const float* __restrict__ W, unsigned short* __restrict__ Wb,
    const float* __restrict__ features, const float* __restrict__ labels,
    const float* __restrict__ label_embed, unsigned short* __restrict__ cb,
    const float* __restrict__ gw, const float* __restrict__ gb,
    float* __restrict__ gating)
{
    __shared__ float smem[CW_TK * CW_TO];      // 32 KiB flat, overlaid per role
    const int bid = blockIdx.x;
    const int t   = threadIdx.x;

    if (bid >= PREP_BLOCKS + GATE_BLOCKS) {
        // ---------------- convert role: W fp32 [e][k][o] -> Wb bf16 [e][o][k]
        const int cwb = bid - (PREP_BLOCKS + GATE_BLOCKS);
        const int o0 = (cwb & 15) * CW_TO;                       // 16 o-tiles
        const int k0 = ((cwb >> 4) % (INDIM / CW_TK)) * CW_TK;   // 40 k-bands
        const int e  = cwb / ((ODIM / CW_TO) * (INDIM / CW_TK));

        // stage: iteration p covers rows p*8..p*8+7; thread t -> row p*8+(t>>5),
        // 16B chunk t&31. LDS linear [64][128] f32: wave-uniform base + lane*16
        // (lane l: (l>>5)*512B + (l&31)*16B = l*16B — exact gload_lds order).
        const int rowi = t >> 5;                  // 0..7
        const int ch   = t & 31;                  // 16B chunk within 512B row
        const float* srcbase = W + (size_t)e * ((size_t)INDIM * ODIM)
                                 + (size_t)k0 * ODIM + o0;
        float* ldsbase = smem + (t >> 6) * 256;   // wave-uniform (2 rows/wave)
        #pragma unroll
        for (int p = 0; p < 8; ++p) {
            gload_lds16(srcbase + (size_t)(p * 8 + rowi) * ODIM + ch * 4,
                        ldsbase + p * 1024);
        }
        __syncthreads();   // vmcnt(0) drain before barrier — wanted here

        // write: o-row = t>>1 (128 rows), k-half h = t&1 (32 k = 64B each;
        // thread pair covers the full 128B line contiguously).
        const int o = t >> 1;
        const int h = t & 1;
        unsigned short* dst = Wb + (size_t)e * ((size_t)ODIM * INDIM)
                                 + (size_t)(o0 + o) * INDIM + k0 + h * 32;
        #pragma unroll
        for (int u = 0; u < 4; ++u) {
            const int kb = h * 32 + u * 8;
            const float* col = smem + (size_t)kb * 128 + o;
            unsigned int w0 = pack2(col[0 * 128], col[1 * 128]);
            unsigned int w1 = pack2(col[2 * 128], col[3 * 128]);
            unsigned int w2 = pack2(col[4 * 128], col[5 * 128]);
            unsigned int w3 = pack2(col[6 * 128], col[7 * 128]);
            ((uint4*)dst)[u] = make_uint4(w0, w1, w2, w3);
        }
    } else if (bid < PREP_BLOCKS) {
        // ---------------- prep role: cb = [features | labels @ label_embed] bf16
        const int b0 = bid * 4;
        float (*lab)[LDIM] = (float(*)[LDIM])smem;
        for (int idx = t; idx < 4 * LDIM; idx += 256) {
            lab[idx / LDIM][idx % LDIM] = labels[(size_t)(b0 + idx / LDIM) * LDIM + (idx % LDIM)];
        }
        __syncthreads();
        {
            const int r = t >> 6, c64 = t & 63;
            const float4* F4 = (const float4*)features;
            #pragma unroll
            for (int ch = 0; ch < 8; ++ch) {
                float4 v = F4[(size_t)(b0 + r) * (FDIM / 4) + c64 + 64 * ch];
                uint2 pk;
                pk.x = pack2(v.x, v.y);
                pk.y = pack2(v.z, v.w);
                *(uint2*)(cb + (size_t)(b0 + r) * INDIM + (size_t)(c64 + 64 * ch) * 4) = pk;
            }
        }
        {
            const int j = 2 * t;
            float acc[4][2] = {{0,0},{0,0},{0,0},{0,0}};
            const float2* le2 = (const float2*)label_embed;
            for (int l = 0; l < LDIM; ++l) {
                float2 le = le2[(size_t)l * (EDIM / 2) + t];
                #pragma unroll
                for (int r = 0; r < 4; ++r) {
                    float lv = lab[r][l];
                    acc[r][0] += lv * le.x;
                    acc[r][1] += lv * le.y;
                }
            }
            #pragma unroll
            for (int r = 0; r < 4; ++r) {
                *(unsigned int*)(cb + (size_t)(b0 + r) * INDIM + FDIM + j) = pack2(acc[r][0], acc[r][1]);
            }
        }
    } else {
        // ---------------- gate role: gating = sigmoid([F | labels@E] @ gw + gb)
        const int b = bid - PREP_BLOCKS;
        float* labs = smem;                               // [80]
        float (*red)[NEXP] = (float(*)[NEXP])(smem + 128);
        if (t < LDIM) labs[t] = labels[(size_t)b * LDIM + t];
        __syncthreads();

        float p[NEXP] = {0,0,0,0,0,0,0,0};
        for (int i = t; i < FDIM; i += 256) {
            float c = features[(size_t)b * FDIM + i];
            const float4* g4 = (const float4*)(gw + (size_t)i * NEXP);
            float4 u = g4[0], v = g4[1];
            p[0] += c * u.x; p[1] += c * u.y; p[2] += c * u.z; p[3] += c * u.w;
            p[4] += c * v.x; p[5] += c * v.y; p[6] += c * v.z; p[7] += c * v.w;
        }
        float le0 = 0.f, le1 = 0.f;
        #pragma unroll 8
        for (int l = 0; l < LDIM; ++l) {
            float lv = labs[l];
            le0 += lv * label_embed[(size_t)l * EDIM + t];
            le1 += lv * label_embed[(size_t)l * EDIM + t + 256];
        }
        {
            const float4* g4 = (const float4*)(gw + (size_t)(FDIM + t) * NEXP);
            float4 u = g4[0], v = g4[1];
            p[0] += le0 * u.x; p[1] += le0 * u.y; p[2] += le0 * u.z; p[3] += le0 * u.w;
            p[4] += le0 * v.x; p[5] += le0 * v.y; p[6] += le0 * v.z; p[7] += le0 * v.w;
            const float4* g5 = (const float4*)(gw + (size_t)(FDIM + 256 + t) * NEXP);
            float4 u2 = g5[0], v2 = g5[1];
            p[0] += le1 * u2.x; p[1] += le1 * u2.y; p[2] += le1 * u2.z; p[3] += le1 * u2.w;
            p[4] += le1 * v2.x; p[5] += le1 * v2.y; p[6] += le1 * v2.z; p[7] += le1 * v2.w;
        }
        const int lane = t & 63, wave = t >> 6;
        #pragma unroll
        for (int e = 0; e < NEXP; ++e) {
            float v = p[e];
            v += __shfl_down(v, 32); v += __shfl_down(v, 16); v += __shfl_down(v, 8);
            v += __shfl_down(v, 4);  v += __shfl_down(v, 2);  v += __shfl_down(v, 1);
            if (lane == 0) red[wave][e] = v;
        }
        __syncthreads();
        if (t < NEXP) {
            float s = red[0][t] + red[1][t] + red[2][t] + red[3][t] + gb[t];
            gating[(size_t)b * NEXP + t] = 1.0f / (1.0f + __expf(-s));
        }
    }
}

// ---------------------------------------------------------------------------
// Kernel 1/2 (retained for the small-ws fallback path only)
// ---------------------------------------------------------------------------
__global__ __launch_bounds__(256) void prep_kernel(
    const float* __restrict__ features, const float* __restrict__ labels,
    const float* __restrict__ label_embed, unsigned short* __restrict__ cb)
{
    const int b0 = blockIdx.x * 4;
    const int t  = threadIdx.x;
    __shared__ float lab[4][LDIM];
    for (int idx = t; idx < 4 * LDIM; idx += 256) {
        lab[idx / LDIM][idx % LDIM] = labels[(size_t)(b0 + idx / LDIM) * LDIM + (idx % LDIM)];
    }
    __syncthreads();

    {
        const int r = t >> 6, c64 = t & 63;
        const float4* F4 = (const float4*)features;
        #pragma unroll
        for (int ch = 0; ch < 8; ++ch) {
            float4 v = F4[(size_t)(b0 + r) * (FDIM / 4) + c64 + 64 * ch];
            uint2 pk;
            pk.x = pack2(v.x, v.y);
            pk.y = pack2(v.z, v.w);
            *(uint2*)(cb + (size_t)(b0 + r) * INDIM + (size_t)(c64 + 64 * ch) * 4) = pk;
        }
    }
    {
        const int j = 2 * t;
        float acc[4][2] = {{0,0},{0,0},{0,0},{0,0}};
        const float2* le2 = (const float2*)label_embed;
        for (int l = 0; l < LDIM; ++l) {
            float2 le = le2[(size_t)l * (EDIM / 2) + t];
            #pragma unroll
            for (int r = 0; r < 4; ++r) {
                float lv = lab[r][l];
                acc[r][0] += lv * le.x;
                acc[r][1] += lv * le.y;
            }
        }
        #pragma unroll
        for (int r = 0; r < 4; ++r) {
            *(unsigned int*)(cb + (size_t)(b0 + r) * INDIM + FDIM + j) = pack2(acc[r][0], acc[r][1]);
        }
    }
}

__global__ __launch_bounds__(256) void gate_kernel(
    const unsigned short* __restrict__ cb, const float* __restrict__ gw,
    const float* __restrict__ gb, float* __restrict__ gating)
{
    const int b = blockIdx.x, t = threadIdx.x;
    float p[NEXP] = {0,0,0,0,0,0,0,0};
    for (int i = t; i < INDIM; i += 256) {
        float c = bf2f(cb[(size_t)b * INDIM + i]);
        const float4* g4 = (const float4*)(gw + (size_t)i * NEXP);
        float4 u = g4[0], v = g4[1];
        p[0] += c * u.x; p[1] += c * u.y; p[2] += c * u.z; p[3] += c * u.w;
        p[4] += c * v.x; p[5] += c * v.y; p[6] += c * v.z; p[7] += c * v.w;
    }
    __shared__ float red[4][NEXP];
    const int lane = t & 63, wave = t >> 6;
    #pragma unroll
    for (int e = 0; e < NEXP; ++e) {
        float v = p[e];
        v += __shfl_down(v, 32); v += __shfl_down(v, 16); v += __shfl_down(v, 8);
        v += __shfl_down(v, 4);  v += __shfl_down(v, 2);  v += __shfl_down(v, 1);
        if (lane == 0) red[wave][e] = v;
    }
    __syncthreads();
    if (t < NEXP) {
        float s = red[0][t] + red[1][t] + red[2][t] + red[3][t] + gb[t];
        gating[(size_t)b * NEXP + t] = 1.0f / (1.0f + __expf(-s));
    }
}

// ---------------------------------------------------------------------------
// Kernel 3 (fast path): 256x256 8-phase pipelined MFMA GEMM (unchanged R6/R7
// K-loop; non-atomic epilogue writes gated+biased partials — R7-confirmed win).
// ---------------------------------------------------------------------------
template<bool ATOMIC>
__global__ __launch_bounds__(512, 2) void moe_gemm8(
    const unsigned short* __restrict__ cb, const unsigned short* __restrict__ Wb,
    const float* __restrict__ gating, const float* __restrict__ eb,
    float* __restrict__ dst)
{
    __shared__ unsigned short As0[256 * 64];   // 32 KiB each, 128 KiB total
    __shared__ unsigned short Bs0[256 * 64];
    __shared__ unsigned short As1[256 * 64];
    __shared__ unsigned short Bs1[256 * 64];

    const int t = threadIdx.x;
    const int lane = t & 63, wave = t >> 6;
    const int n0 = blockIdx.x * BN;
    const int m0 = blockIdx.y * BM;
    const int e  = blockIdx.z;

    const int wmi = wave >> 2;            // 0..1
    const int wni = wave & 3;             // 0..3
    const int wmBase = wmi * 128;
    const int wnBase = wni * 64;
    const int fm = lane & 15, fq = lane >> 4;
    const int fsw = fm & 7;               // row&7 for all fragment rows

    const int srow = t >> 3;                        // 0..63
    const int scn  = (t & 7) ^ (srow & 7);
    const size_t gOff = (size_t)srow * INDIM + (size_t)scn * 8;
    const unsigned short* aS = cb + (size_t)m0 * INDIM + gOff;
    const unsigned short* bS = Wb + (size_t)e * ((size_t)ODIM * INDIM)
                                  + (size_t)n0 * INDIM + gOff;

    #define STAGE4_A(DST, kt) { _Pragma("unroll") for (int q = 0; q < 4; ++q) \
        gload_lds16(aS + (size_t)q * (64 * INDIM) + (size_t)(kt) * 64, (DST) + q * 4096 + wave * 512); }
    #define STAGE4_B(DST, kt) { _Pragma("unroll") for (int q = 0; q < 4; ++q) \
        gload_lds16(bS + (size_t)q * (64 * INDIM) + (size_t)(kt) * 64, (DST) + q * 4096 + wave * 512); }

    #define PH_READ_A(RA, base) { _Pragma("unroll") for (int mi = 0; mi < 4; ++mi) \
        _Pragma("unroll") for (int ks = 0; ks < 2; ++ks) \
            af[mi][ks] = *(const bf16x8*)((RA) + (wmBase + (base) + mi * 16 + fm) * 64 \
                                               + (((ks * 4 + fq) ^ fsw) * 8)); }
    #define PH_READ_B(BF, RB, base) { _Pragma("unroll") for (int ni = 0; ni < 2; ++ni) \
        _Pragma("unroll") for (int ks = 0; ks < 2; ++ks) \
            BF[ni][ks] = *(const bf16x8*)((RB) + (wnBase + (base) + ni * 16 + fm) * 64 \
                                               + (((ks * 4 + fq) ^ fsw) * 8)); }
    #define MFMA16(AI, AJ, BF) { __builtin_amdgcn_s_setprio(1); \
        _Pragma("unroll") for (int mi = 0; mi < 4; ++mi) \
        _Pragma("unroll") for (int ni = 0; ni < 2; ++ni) \
        _Pragma("unroll") for (int ks = 0; ks < 2; ++ks) \
            acc[(AI) + mi][(AJ) + ni] = __builtin_amdgcn_mfma_f32_16x16x32_bf16( \
                af[mi][ks], BF[ni][ks], acc[(AI) + mi][(AJ) + ni], 0, 0, 0); \
        __builtin_amdgcn_s_setprio(0); }

    f32x4 acc[8][4];
    #pragma unroll
    for (int i = 0; i < 8; ++i)
        #pragma unroll
        for (int j = 0; j < 4; ++j) acc[i][j] = (f32x4){0.f, 0.f, 0.f, 0.f};

    bf16x8 af[4][2], bA[2][2], bB[2][2];

    // Prologue: T0 fully -> As0/Bs0 (8), T1's B -> Bs1 (4).
    STAGE4_A(As0, 0); STAGE4_B(Bs0, 0); STAGE4_B(Bs1, 1);
    asm volatile("s_waitcnt vmcnt(4)");   // T0 resident; T1-B stays in flight
    BAR(); SCHED_PIN();

    #define TILE(kt, RA, RB, OA) { \
        /* phase 1: C(mh0,nh0) */ \
        PH_READ_A(RA, 0); \
        PH_READ_B(bA, RB, 0); \
        if ((kt) + 1 < NKT) STAGE4_A(OA, (kt) + 1); \
        BAR(); \
        MFMA16(0, 0, bA); \
        SCHED_PIN(); BAR(); SCHED_PIN(); \
        /* phase 2: C(mh0,nh1) */ \
        PH_READ_B(bB, RB, 32); \
        BAR(); \
        MFMA16(0, 2, bB); \
        SCHED_PIN(); BAR(); SCHED_PIN(); \
        /* phase 3: C(mh1,nh1) */ \
        PH_READ_A(RA, 64); \
        BAR(); \
        MFMA16(4, 2, bB); \
        SCHED_PIN(); BAR(); SCHED_PIN(); \
        /* phase 4: C(mh1,nh0); stage next-next B into cur-B (reads done ph2) */ \
        if ((kt) + 2 < NKT) STAGE4_B(RB, (kt) + 2); \
        BAR(); \
        MFMA16(4, 0, bA); \
        SCHED_PIN(); \
        if ((kt) + 2 < NKT) { asm volatile("s_waitcnt vmcnt(4)"); } \
        else                { asm volatile("s_waitcnt vmcnt(0)"); } \
        BAR(); SCHED_PIN(); \
    }

    for (int kt = 0; kt < NKT; kt += 2) {
        TILE(kt,     As0, Bs0, As1);
        TILE(kt + 1, As1, Bs1, As0);
    }
    #undef TILE
    #undef STAGE4_A
    #undef STAGE4_B
    #undef PH_READ_A
    #undef PH_READ_B
    #undef MFMA16

    // Epilogue: gate-scale + gated bias.
    #pragma unroll
    for (int mi = 0; mi < 8; ++mi) {
        const int grow = m0 + wmBase + mi * 16 + fq * 4;
        const float g0 = gating[(size_t)(grow + 0) * NEXP + e];
        const float g1 = gating[(size_t)(grow + 1) * NEXP + e];
        const float g2 = gating[(size_t)(grow + 2) * NEXP + e];
        const float g3 = gating[(size_t)(grow + 3) * NEXP + e];
        #pragma unroll
        for (int ni = 0; ni < 4; ++ni) {
            const int gcol = n0 + wnBase + ni * 16 + fm;
            const float bias = eb[(size_t)e * ODIM + gcol];
            f32x4 a = acc[mi][ni];
            if (ATOMIC) {
                unsafeAtomicAdd(dst + (size_t)(grow + 0) * ODIM + gcol, g0 * (a.x + bias));
                unsafeAtomicAdd(dst + (size_t)(grow + 1) * ODIM + gcol, g1 * (a.y + bias));
                unsafeAtomicAdd(dst + (size_t)(grow + 2) * ODIM + gcol, g2 * (a.z + bias));
                unsafeAtomicAdd(dst + (size_t)(grow + 3) * ODIM + gcol, g3 * (a.w + bias));
            } else {
                float* pd = dst + ((size_t)e * BATCH + grow) * ODIM + gcol;
                pd[0 * ODIM] = g0 * (a.x + bias);
                pd[1 * ODIM] = g1 * (a.y + bias);
                pd[2 * ODIM] = g2 * (a.z + bias);
                pd[3 * ODIM] = g3 * (a.w + bias);
            }
        }
    }
}

// ---------------------------------------------------------------------------
// Kernel 4: out[m][n] = sum_e parts[e][m][n]. Streaming, float4, ~72 MB.
// ---------------------------------------------------------------------------
__global__ __launch_bounds__(256) void combine_kernel(
    const float* __restrict__ parts, float* __restrict__ out)
{
    const int idx = blockIdx.x * 256 + threadIdx.x;    // one float4 per thread
    const float4* p = (const float4*)parts;
    float4 s = p[idx];
    #pragma unroll
    for (int e = 1; e < NEXP; ++e) {
        float4 v = p[(size_t)e * (BATCH * ODIM / 4) + idx];
        s.x += v.x; s.y += v.y; s.z += v.z; s.w += v.w;
    }
    ((float4*)out)[idx] = s;
}

// ---------------------------------------------------------------------------
// Kernel 3 (fallback, small-ws): in-loop fp32->bf16 W staging (unchanged)
// ---------------------------------------------------------------------------
__global__ __launch_bounds__(256) void moe_gemm_slow(
    const unsigned short* __restrict__ cb, const float* __restrict__ W,
    const float* __restrict__ gating, const float* __restrict__ eb,
    float* __restrict__ out)
{
    __shared__ unsigned short As[128 * 32];
    __shared__ unsigned short Bs[128 * 32];

    const int t = threadIdx.x;
    const int lane = t & 63, wave = t >> 6;
    const int n0 = blockIdx.x * 128;
    const int m0 = blockIdx.y * 128;
    const int e  = blockIdx.z;

    f32x4 acc[4][4];
    #pragma unroll
    for (int i = 0; i < 4; ++i)
        #pragma unroll
        for (int j = 0; j < 4; ++j) acc[i][j] = (f32x4){0.f, 0.f, 0.f, 0.f};

    const int arow = t >> 2, acg = t & 3;
    const unsigned short* ag0 = cb + (size_t)(m0 + arow) * INDIM + acg * 8;
    unsigned short* al0 = As + wave * 512;
    unsigned short* al1 = As + 2048 + wave * 512;

    const int bg = t & 15;
    const int bu = t >> 4;
    const float* wg = W + (size_t)e * ((size_t)INDIM * ODIM) + (size_t)(2 * bg) * ODIM + n0 + bu * 8;
    unsigned int* bl = (unsigned int*)Bs + bg + bu * 128;

    const int fm = lane & 15, fq = lane >> 4;
    const int wn = (wave & 1) * 64;
    const int wm = (wave >> 1) * 64;

    for (int k0 = 0; k0 < INDIM; k0 += 32) {
        __syncthreads();
        gload_lds16(ag0 + k0, al0);
        gload_lds16(ag0 + (size_t)64 * INDIM + k0, al1);
        const float* wp = wg + (size_t)k0 * ODIM;
        float4 r0a = *(const float4*)(wp);
        float4 r0b = *(const float4*)(wp + 4);
        float4 r1a = *(const float4*)(wp + ODIM);
        float4 r1b = *(const float4*)(wp + ODIM + 4);
        bl[0 * 16] = pack2(r0a.x, r1a.x);
        bl[1 * 16] = pack2(r0a.y, r1a.y);
        bl[2 * 16] = pack2(r0a.z, r1a.z);
        bl[3 * 16] = pack2(r0a.w, r1a.w);
        bl[4 * 16] = pack2(r0b.x, r1b.x);
        bl[5 * 16] = pack2(r0b.y, r1b.y);
        bl[6 * 16] = pack2(r0b.z, r1b.z);
        bl[7 * 16] = pack2(r0b.w, r1b.w);
        __syncthreads();

        bf16x8 af[4], bfr[4];
        #pragma unroll
        for (int mi = 0; mi < 4; ++mi)
            af[mi] = *(const bf16x8*)(As + (wm + mi * 16 + fm) * 32 + fq * 8);
        #pragma unroll
        for (int ni = 0; ni < 4; ++ni)
            bfr[ni] = *(const bf16x8*)(Bs + (wn + ni * 16 + fm) * 32 + fq * 8);
        #pragma unroll
        for (int mi = 0; mi < 4; ++mi)
            #pragma unroll
            for (int ni = 0; ni < 4; ++ni)
                acc[mi][ni] = __builtin_amdgcn_mfma_f32_16x16x32_bf16(af[mi], bfr[ni], acc[mi][ni], 0, 0, 0);
    }

    #pragma unroll
    for (int mi = 0; mi < 4; ++mi) {
        const int grow = m0 + wm + mi * 16 + fq * 4;
        const float g0 = gating[(size_t)(grow + 0) * NEXP + e];
        const float g1 = gating[(size_t)(grow + 1) * NEXP + e];
        const float g2 = gating[(size_t)(grow + 2) * NEXP + e];
        const float g3 = gating[(size_t)(grow + 3) * NEXP + e];
        #pragma unroll
        for (int ni = 0; ni < 4; ++ni) {
            const int gcol = n0 + wn + ni * 16 + fm;
            const float bias = eb[(size_t)e * ODIM + gcol];
            f32x4 a = acc[mi][ni];
            unsafeAtomicAdd(out + (size_t)(grow + 0) * ODIM + gcol, g0 * (a.x + bias));
            unsafeAtomicAdd(out + (size_t)(grow + 1) * ODIM + gcol, g1 * (a.y + bias));
            unsafeAtomicAdd(out + (size_t)(grow + 2) * ODIM + gcol, g2 * (a.z + bias));
            unsafeAtomicAdd(out + (size_t)(grow + 3) * ODIM + gcol, g3 * (a.w + bias));
        }
    }
}

// ---------------------------------------------------------------------------
extern "C" void kernel_launch(void* const* d_in, const int* in_sizes, int n_in,
                              void* d_out, int out_size, void* d_ws, size_t ws_size,
                              hipStream_t stream) {
    const float* features    = (const float*)d_in[0];
    const float* labels      = (const float*)d_in[1];
    const float* label_embed = (const float*)d_in[2];
    const float* gate_w      = (const float*)d_in[3];
    const float* gate_b      = (const float*)d_in[4];
    const float* expert_w    = (const float*)d_in[5];
    const float* expert_b    = (const float*)d_in[6];
    float* out = (float*)d_out;

    // ws layout: Wb bf16 [8][2048][2560] | cb bf16 [1024][2560] | gating f32 |
    //            parts f32 [8][1024][2048]  (parts only on the fast2 path)
    const size_t wb_bytes = (size_t)NEXP * ODIM * INDIM * 2;        // 83,886,080
    const size_t cb_bytes = (size_t)BATCH * INDIM * 2;              //  5,242,880
    const size_t gt_bytes = (size_t)BATCH * NEXP * 4;               //     32,768
    const size_t pt_bytes = (size_t)NEXP * BATCH * ODIM * 4;        // 67,108,864
    const bool fast  = ws_size >= wb_bytes + cb_bytes + gt_bytes;
    const bool fast2 = ws_size >= wb_bytes + cb_bytes + gt_bytes + pt_bytes;

    if (fast) {
        unsigned short* Wb = (unsigned short*)d_ws;
        unsigned short* cb = (unsigned short*)((char*)d_ws + wb_bytes);
        float* gating = (float*)((char*)d_ws + wb_bytes + cb_bytes);
        float* parts  = (float*)((char*)d_ws + wb_bytes + cb_bytes + gt_bytes);
        front_kernel<<<FRONT_BLOCKS, 256, 0, stream>>>(
            expert_w, Wb, features, labels, label_embed, cb, gate_w, gate_b, gating);
        if (fast2) {
            moe_gemm8<false><<<dim3(ODIM / BN, BATCH / BM, NEXP), 512, 0, stream>>>(cb, Wb, gating, expert_b, parts);
            combine_kernel<<<(BATCH * ODIM / 4) / 256, 256, 0, stream>>>(parts, out);
        } else {
            hipMemsetAsync(d_out, 0, (size_t)BATCH * ODIM * sizeof(float), stream);
            moe_gemm8<true><<<dim3(ODIM / BN, BATCH / BM, NEXP), 512, 0, stream>>>(cb, Wb, gating, expert_b, out);
        }
    } else {
        unsigned short* cb = (unsigned short*)d_ws;
        float* gating = (float*)((char*)d_ws + cb_bytes);
        hipMemsetAsync(d_out, 0, (size_t)BATCH * ODIM * sizeof(float), stream);
        prep_kernel<<<BATCH / 4, 256, 0, stream>>>(features, labels, label_embed, cb);
        gate_kernel<<<BATCH, 256, 0, stream>>>(cb, gate_w, gate_b, gating);
        moe_gemm_slow<<<dim3(ODIM / 128, BATCH / 128, NEXP), 256, 0, stream>>>(cb, expert_w, gating, expert_b, out);
    }
}

// Round 17
// 371.772 us; speedup vs baseline: 1.0035x; 1.0015x over previous
//
#include <hip/hip_runtime.h>
#include <hip/hip_bf16.h>

// Problem constants
#define BATCH   1024
#define FDIM    2048
#define LDIM    80
#define EDIM    512
#define ODIM    2048
#define NEXP    8
#define INDIM   2560   // FDIM + EDIM

// GEMM geometry (8-phase 256^2 template)
#define BM      256
#define BN      256
#define BK      64
#define NKT     (INDIM / BK)   // 40 K-tiles

typedef __bf16 bf16x8 __attribute__((ext_vector_type(8)));
typedef float  f32x4  __attribute__((ext_vector_type(4)));

__device__ __forceinline__ unsigned int pack2(float lo, float hi) {
    __hip_bfloat162 h = __float22bfloat162_rn(make_float2(lo, hi));
    unsigned int u;
    __builtin_memcpy(&u, &h, 4);
    return u;
}
__device__ __forceinline__ float bf2f(unsigned short h) {
    return __uint_as_float((unsigned int)h << 16);
}
__device__ __forceinline__ void gload_lds16(const void* g, void* l) {
    __builtin_amdgcn_global_load_lds(
        (__attribute__((address_space(1))) void*)g,
        (__attribute__((address_space(3))) void*)l,
        16, 0, 0);
}

#define BAR()       __builtin_amdgcn_s_barrier()
#define SCHED_PIN() __builtin_amdgcn_sched_barrier(0)

// convert tile geometry v4 (R15-measured: front dropped out of top-5)
#define CW_TK 64    // k rows per tile
#define CW_TO 128   // o cols per tile
#define CW_BLOCKS  ((ODIM / CW_TO) * (INDIM / CW_TK) * NEXP)   // 16*40*8 = 5120
#define PREP_BLOCKS (BATCH / 4)                                 // 256
#define GATE_BLOCKS (BATCH)                                     // 1024
#define FRONT_BLOCKS (CW_BLOCKS + PREP_BLOCKS + GATE_BLOCKS)    // 6400

// ---------------------------------------------------------------------------
// Kernel F (fused front): prep + gate + convert_w in ONE launch (unchanged).
// ---------------------------------------------------------------------------
__global__ __launch_bounds__(256) void front_kernel(
    const float* __restrict__ W, unsigned short* __restrict__ Wb,
    const float* __restrict__ features, const float* __restrict__ labels,
    const float* __restrict__ label_embed, unsigned short* __restrict__ cb,
    const float* __restrict__ gw, const float* __restrict__ gb,
    float* __restrict__ gating)
{
    __shared__ float smem[CW_TK * CW_TO];      // 32 KiB flat, overlaid per role
    const int bid = blockIdx.x;
    const int t   = threadIdx.x;

    if (bid >= PREP_BLOCKS + GATE_BLOCKS) {
        // ---------------- convert role: W fp32 [e][k][o] -> Wb bf16 [e][o][k]
        const int cwb = bid - (PREP_BLOCKS + GATE_BLOCKS);
        const int o0 = (cwb & 15) * CW_TO;                       // 16 o-tiles
        const int k0 = ((cwb >> 4) % (INDIM / CW_TK)) * CW_TK;   // 40 k-bands
        const int e  = cwb / ((ODIM / CW_TO) * (INDIM / CW_TK));

        const int rowi = t >> 5;                  // 0..7
        const int ch   = t & 31;                  // 16B chunk within 512B row
        const float* srcbase = W + (size_t)e * ((size_t)INDIM * ODIM)
                                 + (size_t)k0 * ODIM + o0;
        float* ldsbase = smem + (t >> 6) * 256;   // wave-uniform (2 rows/wave)
        #pragma unroll
        for (int p = 0; p < 8; ++p) {
            gload_lds16(srcbase + (size_t)(p * 8 + rowi) * ODIM + ch * 4,
                        ldsbase + p * 1024);
        }
        __syncthreads();   // vmcnt(0) drain before barrier — wanted here

        const int o = t >> 1;
        const int h = t & 1;
        unsigned short* dst = Wb + (size_t)e * ((size_t)ODIM * INDIM)
                                 + (size_t)(o0 + o) * INDIM + k0 + h * 32;
        #pragma unroll
        for (int u = 0; u < 4; ++u) {
            const int kb = h * 32 + u * 8;
            const float* col = smem + (size_t)kb * 128 + o;
            unsigned int w0 = pack2(col[0 * 128], col[1 * 128]);
            unsigned int w1 = pack2(col[2 * 128], col[3 * 128]);
            unsigned int w2 = pack2(col[4 * 128], col[5 * 128]);
            unsigned int w3 = pack2(col[6 * 128], col[7 * 128]);
            ((uint4*)dst)[u] = make_uint4(w0, w1, w2, w3);
        }
    } else if (bid < PREP_BLOCKS) {
        // ---------------- prep role: cb = [features | labels @ label_embed] bf16
        const int b0 = bid * 4;
        float (*lab)[LDIM] = (float(*)[LDIM])smem;
        for (int idx = t; idx < 4 * LDIM; idx += 256) {
            lab[idx / LDIM][idx % LDIM] = labels[(size_t)(b0 + idx / LDIM) * LDIM + (idx % LDIM)];
        }
        __syncthreads();
        {
            const int r = t >> 6, c64 = t & 63;
            const float4* F4 = (const float4*)features;
            #pragma unroll
            for (int ch = 0; ch < 8; ++ch) {
                float4 v = F4[(size_t)(b0 + r) * (FDIM / 4) + c64 + 64 * ch];
                uint2 pk;
                pk.x = pack2(v.x, v.y);
                pk.y = pack2(v.z, v.w);
                *(uint2*)(cb + (size_t)(b0 + r) * INDIM + (size_t)(c64 + 64 * ch) * 4) = pk;
            }
        }
        {
            const int j = 2 * t;
            float acc[4][2] = {{0,0},{0,0},{0,0},{0,0}};
            const float2* le2 = (const float2*)label_embed;
            for (int l = 0; l < LDIM; ++l) {
                float2 le = le2[(size_t)l * (EDIM / 2) + t];
                #pragma unroll
                for (int r = 0; r < 4; ++r) {
                    float lv = lab[r][l];
                    acc[r][0] += lv * le.x;
                    acc[r][1] += lv * le.y;
                }
            }
            #pragma unroll
            for (int r = 0; r < 4; ++r) {
                *(unsigned int*)(cb + (size_t)(b0 + r) * INDIM + FDIM + j) = pack2(acc[r][0], acc[r][1]);
            }
        }
    } else {
        // ---------------- gate role: gating = sigmoid([F | labels@E] @ gw + gb)
        const int b = bid - PREP_BLOCKS;
        float* labs = smem;                               // [80]
        float (*red)[NEXP] = (float(*)[NEXP])(smem + 128);
        if (t < LDIM) labs[t] = labels[(size_t)b * LDIM + t];
        __syncthreads();

        float p[NEXP] = {0,0,0,0,0,0,0,0};
        for (int i = t; i < FDIM; i += 256) {
            float c = features[(size_t)b * FDIM + i];
            const float4* g4 = (const float4*)(gw + (size_t)i * NEXP);
            float4 u = g4[0], v = g4[1];
            p[0] += c * u.x; p[1] += c * u.y; p[2] += c * u.z; p[3] += c * u.w;
            p[4] += c * v.x; p[5] += c * v.y; p[6] += c * v.z; p[7] += c * v.w;
        }
        float le0 = 0.f, le1 = 0.f;
        #pragma unroll 8
        for (int l = 0; l < LDIM; ++l) {
            float lv = labs[l];
            le0 += lv * label_embed[(size_t)l * EDIM + t];
            le1 += lv * label_embed[(size_t)l * EDIM + t + 256];
        }
        {
            const float4* g4 = (const float4*)(gw + (size_t)(FDIM + t) * NEXP);
            float4 u = g4[0], v = g4[1];
            p[0] += le0 * u.x; p[1] += le0 * u.y; p[2] += le0 * u.z; p[3] += le0 * u.w;
            p[4] += le0 * v.x; p[5] += le0 * v.y; p[6] += le0 * v.z; p[7] += le0 * v.w;
            const float4* g5 = (const float4*)(gw + (size_t)(FDIM + 256 + t) * NEXP);
            float4 u2 = g5[0], v2 = g5[1];
            p[0] += le1 * u2.x; p[1] += le1 * u2.y; p[2] += le1 * u2.z; p[3] += le1 * u2.w;
            p[4] += le1 * v2.x; p[5] += le1 * v2.y; p[6] += le1 * v2.z; p[7] += le1 * v2.w;
        }
        const int lane = t & 63, wave = t >> 6;
        #pragma unroll
        for (int e = 0; e < NEXP; ++e) {
            float v = p[e];
            v += __shfl_down(v, 32); v += __shfl_down(v, 16); v += __shfl_down(v, 8);
            v += __shfl_down(v, 4);  v += __shfl_down(v, 2);  v += __shfl_down(v, 1);
            if (lane == 0) red[wave][e] = v;
        }
        __syncthreads();
        if (t < NEXP) {
            float s = red[0][t] + red[1][t] + red[2][t] + red[3][t] + gb[t];
            gating[(size_t)b * NEXP + t] = 1.0f / (1.0f + __expf(-s));
        }
    }
}

// ---------------------------------------------------------------------------
// Kernel 1/2 (retained for the small-ws fallback path only)
// ---------------------------------------------------------------------------
__global__ __launch_bounds__(256) void prep_kernel(
    const float* __restrict__ features, const float* __restrict__ labels,
    const float* __restrict__ label_embed, unsigned short* __restrict__ cb)
{
    const int b0 = blockIdx.x * 4;
    const int t  = threadIdx.x;
    __shared__ float lab[4][LDIM];
    for (int idx = t; idx < 4 * LDIM; idx += 256) {
        lab[idx / LDIM][idx % LDIM] = labels[(size_t)(b0 + idx / LDIM) * LDIM + (idx % LDIM)];
    }
    __syncthreads();

    {
        const int r = t >> 6, c64 = t & 63;
        const float4* F4 = (const float4*)features;
        #pragma unroll
        for (int ch = 0; ch < 8; ++ch) {
            float4 v = F4[(size_t)(b0 + r) * (FDIM / 4) + c64 + 64 * ch];
            uint2 pk;
            pk.x = pack2(v.x, v.y);
            pk.y = pack2(v.z, v.w);
            *(uint2*)(cb + (size_t)(b0 + r) * INDIM + (size_t)(c64 + 64 * ch) * 4) = pk;
        }
    }
    {
        const int j = 2 * t;
        float acc[4][2] = {{0,0},{0,0},{0,0},{0,0}};
        const float2* le2 = (const float2*)label_embed;
        for (int l = 0; l < LDIM; ++l) {
            float2 le = le2[(size_t)l * (EDIM / 2) + t];
            #pragma unroll
            for (int r = 0; r < 4; ++r) {
                float lv = lab[r][l];
                acc[r][0] += lv * le.x;
                acc[r][1] += lv * le.y;
            }
        }
        #pragma unroll
        for (int r = 0; r < 4; ++r) {
            *(unsigned int*)(cb + (size_t)(b0 + r) * INDIM + FDIM + j) = pack2(acc[r][0], acc[r][1]);
        }
    }
}

__global__ __launch_bounds__(256) void gate_kernel(
    const unsigned short* __restrict__ cb, const float* __restrict__ gw,
    const float* __restrict__ gb, float* __restrict__ gating)
{
    const int b = blockIdx.x, t = threadIdx.x;
    float p[NEXP] = {0,0,0,0,0,0,0,0};
    for (int i = t; i < INDIM; i += 256) {
        float c = bf2f(cb[(size_t)b * INDIM + i]);
        const float4* g4 = (const float4*)(gw + (size_t)i * NEXP);
        float4 u = g4[0], v = g4[1];
        p[0] += c * u.x; p[1] += c * u.y; p[2] += c * u.z; p[3] += c * u.w;
        p[4] += c * v.x; p[5] += c * v.y; p[6] += c * v.z; p[7] += c * v.w;
    }
    __shared__ float red[4][NEXP];
    const int lane = t & 63, wave = t >> 6;
    #pragma unroll
    for (int e = 0; e < NEXP; ++e) {
        float v = p[e];
        v += __shfl_down(v, 32); v += __shfl_down(v, 16); v += __shfl_down(v, 8);
        v += __shfl_down(v, 4);  v += __shfl_down(v, 2);  v += __shfl_down(v, 1);
        if (lane == 0) red[wave][e] = v;
    }
    __syncthreads();
    if (t < NEXP) {
        float s = red[0][t] + red[1][t] + red[2][t] + red[3][t] + gb[t];
        gating[(size_t)b * NEXP + t] = 1.0f / (1.0f + __expf(-s));
    }
}

// ---------------------------------------------------------------------------
// Kernel 3 (fast path): 256x256 8-phase pipelined MFMA GEMM.
// R16 FIX: the per-phase A staging must follow QUARTER death, not halves.
// A-read regions: ph1 reads quarters {0,2} (wmi0: rows 0-63, wmi1: 128-191);
// ph3 reads quarters {1,3} (rows 64-127 / 192-255). R16 staged half0={q0,q1}
// at ph2, clobbering q1 before ph3's read -> absmax 23.75. Correct schedule:
//   ph1: A(kt+1) q{1,3} -> other buf  (fully dead: prior tile complete)
//   ph2: A(kt+2) q{0,2} -> cur buf    (dead after ph1)
//   ph3: B(kt+2) q{0,1} -> cur buf    (all B reads done at ph2)
//   ph4: B(kt+2) q{2,3} -> cur buf; s_waitcnt vmcnt(6)
// vmcnt(6) at ph4 leaves ph2/ph3/ph4's 6 loads in flight; everything older
// (incl. A(kt+1) q{1,3} from ph1 and A(kt+1) q{0,2} from (kt-1).ph2) drains
// => T{kt+1} fully resident before its first read.
// ---------------------------------------------------------------------------
template<bool ATOMIC>
__global__ __launch_bounds__(512, 2) void moe_gemm8(
    const unsigned short* __restrict__ cb, const unsigned short* __restrict__ Wb,
    const float* __restrict__ gating, const float* __restrict__ eb,
    float* __restrict__ dst)
{
    __shared__ unsigned short As0[256 * 64];   // 32 KiB each, 128 KiB total
    __shared__ unsigned short Bs0[256 * 64];
    __shared__ unsigned short As1[256 * 64];
    __shared__ unsigned short Bs1[256 * 64];

    const int t = threadIdx.x;
    const int lane = t & 63, wave = t >> 6;
    const int n0 = blockIdx.x * BN;
    const int m0 = blockIdx.y * BM;
    const int e  = blockIdx.z;

    const int wmi = wave >> 2;            // 0..1
    const int wni = wave & 3;             // 0..3
    const int wmBase = wmi * 128;
    const int wnBase = wni * 64;
    const int fm = lane & 15, fq = lane >> 4;
    const int fsw = fm & 7;               // row&7 for all fragment rows

    const int srow = t >> 3;                        // 0..63
    const int scn  = (t & 7) ^ (srow & 7);
    const size_t gOff = (size_t)srow * INDIM + (size_t)scn * 8;
    const unsigned short* aS = cb + (size_t)m0 * INDIM + gOff;
    const unsigned short* bS = Wb + (size_t)e * ((size_t)ODIM * INDIM)
                                  + (size_t)n0 * INDIM + gOff;

    // 2-load QUARTER-PAIR stages (quarter q = rows q*64..q*64+63).
    #define STAGE_A2Q(DST, kt, qa, qb) { \
        gload_lds16(aS + (size_t)(qa) * (64 * INDIM) + (size_t)(kt) * 64, (DST) + (qa) * 4096 + wave * 512); \
        gload_lds16(aS + (size_t)(qb) * (64 * INDIM) + (size_t)(kt) * 64, (DST) + (qb) * 4096 + wave * 512); }
    #define STAGE_B2Q(DST, kt, qa, qb) { \
        gload_lds16(bS + (size_t)(qa) * (64 * INDIM) + (size_t)(kt) * 64, (DST) + (qa) * 4096 + wave * 512); \
        gload_lds16(bS + (size_t)(qb) * (64 * INDIM) + (size_t)(kt) * 64, (DST) + (qb) * 4096 + wave * 512); }

    #define PH_READ_A(RA, base) { _Pragma("unroll") for (int mi = 0; mi < 4; ++mi) \
        _Pragma("unroll") for (int ks = 0; ks < 2; ++ks) \
            af[mi][ks] = *(const bf16x8*)((RA) + (wmBase + (base) + mi * 16 + fm) * 64 \
                                               + (((ks * 4 + fq) ^ fsw) * 8)); }
    #define PH_READ_B(BF, RB, base) { _Pragma("unroll") for (int ni = 0; ni < 2; ++ni) \
        _Pragma("unroll") for (int ks = 0; ks < 2; ++ks) \
            BF[ni][ks] = *(const bf16x8*)((RB) + (wnBase + (base) + ni * 16 + fm) * 64 \
                                               + (((ks * 4 + fq) ^ fsw) * 8)); }
    #define MFMA16(AI, AJ, BF) { __builtin_amdgcn_s_setprio(1); \
        _Pragma("unroll") for (int mi = 0; mi < 4; ++mi) \
        _Pragma("unroll") for (int ni = 0; ni < 2; ++ni) \
        _Pragma("unroll") for (int ks = 0; ks < 2; ++ks) \
            acc[(AI) + mi][(AJ) + ni] = __builtin_amdgcn_mfma_f32_16x16x32_bf16( \
                af[mi][ks], BF[ni][ks], acc[(AI) + mi][(AJ) + ni], 0, 0, 0); \
        __builtin_amdgcn_s_setprio(0); }

    f32x4 acc[8][4];
    #pragma unroll
    for (int i = 0; i < 8; ++i)
        #pragma unroll
        for (int j = 0; j < 4; ++j) acc[i][j] = (f32x4){0.f, 0.f, 0.f, 0.f};

    bf16x8 af[4][2], bA[2][2], bB[2][2];

    // Prologue (14 loads): T0 full (8) + T1.B full (4) + T1.A q{0,2} (2).
    // vmcnt(6) drains the 8 oldest (= all of T0); T1's 6 stay in flight.
    // T1.A q{1,3} is staged at T0.ph1 — matching steady state.
    STAGE_A2Q(As0, 0, 0, 1); STAGE_A2Q(As0, 0, 2, 3);
    STAGE_B2Q(Bs0, 0, 0, 1); STAGE_B2Q(Bs0, 0, 2, 3);
    STAGE_B2Q(Bs1, 1, 0, 1); STAGE_B2Q(Bs1, 1, 2, 3);
    STAGE_A2Q(As1, 1, 0, 2);
    asm volatile("s_waitcnt vmcnt(6)");
    BAR(); SCHED_PIN();

    #define TILE(kt, RA, RB, OA, OB) { \
        /* phase 1: C(mh0,nh0); stage A(kt+1) q{1,3} -> other buf */ \
        PH_READ_A(RA, 0); \
        PH_READ_B(bA, RB, 0); \
        if ((kt) + 1 < NKT) STAGE_A2Q(OA, (kt) + 1, 1, 3); \
        BAR(); \
        MFMA16(0, 0, bA); \
        SCHED_PIN(); BAR(); SCHED_PIN(); \
        /* phase 2: C(mh0,nh1); stage A(kt+2) q{0,2} -> cur (dead after ph1) */ \
        PH_READ_B(bB, RB, 32); \
        if ((kt) + 2 < NKT) STAGE_A2Q(RA, (kt) + 2, 0, 2); \
        BAR(); \
        MFMA16(0, 2, bB); \
        SCHED_PIN(); BAR(); SCHED_PIN(); \
        /* phase 3: C(mh1,nh1); stage B(kt+2) q{0,1} (B reads done ph2) */ \
        PH_READ_A(RA, 64); \
        if ((kt) + 2 < NKT) STAGE_B2Q(RB, (kt) + 2, 0, 1); \
        BAR(); \
        MFMA16(4, 2, bB); \
        SCHED_PIN(); BAR(); SCHED_PIN(); \
        /* phase 4: C(mh1,nh0); stage B(kt+2) q{2,3}; counted wait */ \
        if ((kt) + 2 < NKT) STAGE_B2Q(RB, (kt) + 2, 2, 3); \
        BAR(); \
        MFMA16(4, 0, bA); \
        SCHED_PIN(); \
        if ((kt) + 2 < NKT) { asm volatile("s_waitcnt vmcnt(6)"); } \
        else                { asm volatile("s_waitcnt vmcnt(0)"); } \
        BAR(); SCHED_PIN(); \
    }

    for (int kt = 0; kt < NKT; kt += 2) {
        TILE(kt,     As0, Bs0, As1, Bs1);
        TILE(kt + 1, As1, Bs1, As0, Bs0);
    }
    #undef TILE
    #undef STAGE_A2Q
    #undef STAGE_B2Q
    #undef PH_READ_A
    #undef PH_READ_B
    #undef MFMA16

    // Epilogue: gate-scale + gated bias.
    #pragma unroll
    for (int mi = 0; mi < 8; ++mi) {
        const int grow = m0 + wmBase + mi * 16 + fq * 4;
        const float g0 = gating[(size_t)(grow + 0) * NEXP + e];
        const float g1 = gating[(size_t)(grow + 1) * NEXP + e];
        const float g2 = gating[(size_t)(grow + 2) * NEXP + e];
        const float g3 = gating[(size_t)(grow + 3) * NEXP + e];
        #pragma unroll
        for (int ni = 0; ni < 4; ++ni) {
            const int gcol = n0 + wnBase + ni * 16 + fm;
            const float bias = eb[(size_t)e * ODIM + gcol];
            f32x4 a = acc[mi][ni];
            if (ATOMIC) {
                unsafeAtomicAdd(dst + (size_t)(grow + 0) * ODIM + gcol, g0 * (a.x + bias));
                unsafeAtomicAdd(dst + (size_t)(grow + 1) * ODIM + gcol, g1 * (a.y + bias));
                unsafeAtomicAdd(dst + (size_t)(grow + 2) * ODIM + gcol, g2 * (a.z + bias));
                unsafeAtomicAdd(dst + (size_t)(grow + 3) * ODIM + gcol, g3 * (a.w + bias));
            } else {
                float* pd = dst + ((size_t)e * BATCH + grow) * ODIM + gcol;
                pd[0 * ODIM] = g0 * (a.x + bias);
                pd[1 * ODIM] = g1 * (a.y + bias);
                pd[2 * ODIM] = g2 * (a.z + bias);
                pd[3 * ODIM] = g3 * (a.w + bias);
            }
        }
    }
}

// ---------------------------------------------------------------------------
// Kernel 4: out[m][n] = sum_e parts[e][m][n]. Streaming, float4, ~72 MB.
// ---------------------------------------------------------------------------
__global__ __launch_bounds__(256) void combine_kernel(
    const float* __restrict__ parts, float* __restrict__ out)
{
    const int idx = blockIdx.x * 256 + threadIdx.x;    // one float4 per thread
    const float4* p = (const float4*)parts;
    float4 s = p[idx];
    #pragma unroll
    for (int e = 1; e < NEXP; ++e) {
        float4 v = p[(size_t)e * (BATCH * ODIM / 4) + idx];
        s.x += v.x; s.y += v.y; s.z += v.z; s.w += v.w;
    }
    ((float4*)out)[idx] = s;
}

// ---------------------------------------------------------------------------
// Kernel 3 (fallback, small-ws): in-loop fp32->bf16 W staging (unchanged)
// ---------------------------------------------------------------------------
__global__ __launch_bounds__(256) void moe_gemm_slow(
    const unsigned short* __restrict__ cb, const float* __restrict__ W,
    const float* __restrict__ gating, const float* __restrict__ eb,
    float* __restrict__ out)
{
    __shared__ unsigned short As[128 * 32];
    __shared__ unsigned short Bs[128 * 32];

    const int t = threadIdx.x;
    const int lane = t & 63, wave = t >> 6;
    const int n0 = blockIdx.x * 128;
    const int m0 = blockIdx.y * 128;
    const int e  = blockIdx.z;

    f32x4 acc[4][4];
    #pragma unroll
    for (int i = 0; i < 4; ++i)
        #pragma unroll
        for (int j = 0; j < 4; ++j) acc[i][j] = (f32x4){0.f, 0.f, 0.f, 0.f};

    const int arow = t >> 2, acg = t & 3;
    const unsigned short* ag0 = cb + (size_t)(m0 + arow) * INDIM + acg * 8;
    unsigned short* al0 = As + wave * 512;
    unsigned short* al1 = As + 2048 + wave * 512;

    const int bg = t & 15;
    const int bu = t >> 4;
    const float* wg = W + (size_t)e * ((size_t)INDIM * ODIM) + (size_t)(2 * bg) * ODIM + n0 + bu * 8;
    unsigned int* bl = (unsigned int*)Bs + bg + bu * 128;

    const int fm = lane & 15, fq = lane >> 4;
    const int wn = (wave & 1) * 64;
    const int wm = (wave >> 1) * 64;

    for (int k0 = 0; k0 < INDIM; k0 += 32) {
        __syncthreads();
        gload_lds16(ag0 + k0, al0);
        gload_lds16(ag0 + (size_t)64 * INDIM + k0, al1);
        const float* wp = wg + (size_t)k0 * ODIM;
        float4 r0a = *(const float4*)(wp);
        float4 r0b = *(const float4*)(wp + 4);
        float4 r1a = *(const float4*)(wp + ODIM);
        float4 r1b = *(const float4*)(wp + ODIM + 4);
        bl[0 * 16] = pack2(r0a.x, r1a.x);
        bl[1 * 16] = pack2(r0a.y, r1a.y);
        bl[2 * 16] = pack2(r0a.z, r1a.z);
        bl[3 * 16] = pack2(r0a.w, r1a.w);
        bl[4 * 16] = pack2(r0b.x, r1b.x);
        bl[5 * 16] = pack2(r0b.y, r1b.y);
        bl[6 * 16] = pack2(r0b.z, r1b.z);
        bl[7 * 16] = pack2(r0b.w, r1b.w);
        __syncthreads();

        bf16x8 af[4], bfr[4];
        #pragma unroll
        for (int mi = 0; mi < 4; ++mi)
            af[mi] = *(const bf16x8*)(As + (wm + mi * 16 + fm) * 32 + fq * 8);
        #pragma unroll
        for (int ni = 0; ni < 4; ++ni)
            bfr[ni] = *(const bf16x8*)(Bs + (wn + ni * 16 + fm) * 32 + fq * 8);
        #pragma unroll
        for (int mi = 0; mi < 4; ++mi)
            #pragma unroll
            for (int ni = 0; ni < 4; ++ni)
                acc[mi][ni] = __builtin_amdgcn_mfma_f32_16x16x32_bf16(af[mi], bfr[ni], acc[mi][ni], 0, 0, 0);
    }

    #pragma unroll
    for (int mi = 0; mi < 4; ++mi) {
        const int grow = m0 + wm + mi * 16 + fq * 4;
        const float g0 = gating[(size_t)(grow + 0) * NEXP + e];
        const float g1 = gating[(size_t)(grow + 1) * NEXP + e];
        const float g2 = gating[(size_t)(grow + 2) * NEXP + e];
        const float g3 = gating[(size_t)(grow + 3) * NEXP + e];
        #pragma unroll
        for (int ni = 0; ni < 4; ++ni) {
            const int gcol = n0 + wn + ni * 16 + fm;
            const float bias = eb[(size_t)e * ODIM + gcol];
            f32x4 a = acc[mi][ni];
            unsafeAtomicAdd(out + (size_t)(grow + 0) * ODIM + gcol, g0 * (a.x + bias));
            unsafeAtomicAdd(out + (size_t)(grow + 1) * ODIM + gcol, g1 * (a.y + bias));
            unsafeAtomicAdd(out + (size_t)(grow + 2) * ODIM + gcol, g2 * (a.z + bias));
            unsafeAtomicAdd(out + (size_t)(grow + 3) * ODIM + gcol, g3 * (a.w + bias));
        }
    }
}

// ---------------------------------------------------------------------------
extern "C" void kernel_launch(void* const* d_in, const int* in_sizes, int n_in,
                              void* d_out, int out_size, void* d_ws, size_t ws_size,
                              hipStream_t stream) {
    const float* features    = (const float*)d_in[0];
    const float* labels      = (const float*)d_in[1];
    const float* label_embed = (const float*)d_in[2];
    const float* gate_w      = (const float*)d_in[3];
    const float* gate_b      = (const float*)d_in[4];
    const float* expert_w    = (const float*)d_in[5];
    const float* expert_b    = (const float*)d_in[6];
    float* out = (float*)d_out;

    // ws layout: Wb bf16 [8][2048][2560] | cb bf16 [1024][2560] | gating f32 |
    //            parts f32 [8][1024][2048]  (parts only on the fast2 path)
    const size_t wb_bytes = (size_t)NEXP * ODIM * INDIM * 2;        // 83,886,080
    const size_t cb_bytes = (size_t)BATCH * INDIM * 2;              //  5,242,880
    const size_t gt_bytes = (size_t)BATCH * NEXP * 4;               //     32,768
    const size_t pt_bytes = (size_t)NEXP * BATCH * ODIM * 4;        // 67,108,864
    const bool fast  = ws_size >= wb_bytes + cb_bytes + gt_bytes;
    const bool fast2 = ws_size >= wb_bytes + cb_bytes + gt_bytes + pt_bytes;

    if (fast) {
        unsigned short* Wb = (unsigned short*)d_ws;
        unsigned short* cb = (unsigned short*)((char*)d_ws + wb_bytes);
        float* gating = (float*)((char*)d_ws + wb_bytes + cb_bytes);
        float* parts  = (float*)((char*)d_ws + wb_bytes + cb_bytes + gt_bytes);
        front_kernel<<<FRONT_BLOCKS, 256, 0, stream>>>(
            expert_w, Wb, features, labels, label_embed, cb, gate_w, gate_b, gating);
        if (fast2) {
            moe_gemm8<false><<<dim3(ODIM / BN, BATCH / BM, NEXP), 512, 0, stream>>>(cb, Wb, gating, expert_b, parts);
            combine_kernel<<<(BATCH * ODIM / 4) / 256, 256, 0, stream>>>(parts, out);
        } else {
            hipMemsetAsync(d_out, 0, (size_t)BATCH * ODIM * sizeof(float), stream);
            moe_gemm8<true><<<dim3(ODIM / BN, BATCH / BM, NEXP), 512, 0, stream>>>(cb, Wb, gating, expert_b, out);
        }
    } else {
        unsigned short* cb = (unsigned short*)d_ws;
        float* gating = (float*)((char*)d_ws + cb_bytes);
        hipMemsetAsync(d_out, 0, (size_t)BATCH * ODIM * sizeof(float), stream);
        prep_kernel<<<BATCH / 4, 256, 0, stream>>>(features, labels, label_embed, cb);
        gate_kernel<<<BATCH, 256, 0, stream>>>(cb, gate_w, gate_b, gating);
        moe_gemm_slow<<<dim3(ODIM / 128, BATCH / 128, NEXP), 256, 0, stream>>>(cb, expert_w, gating, expert_b, out);
    }
}